// Round 19
// baseline (36.350 us; speedup 1.0000x reference)
//
#include <hip/hip_runtime.h>
#include <hip/hip_bf16.h>
#include <math.h>

#define DEV __device__ __forceinline__

typedef __attribute__((ext_vector_type(8))) short short8v;
typedef __attribute__((ext_vector_type(4))) float f32x4;

DEV unsigned short f2bf(float x) {
    unsigned u = __float_as_uint(x);
    return (unsigned short)((u + 0x7fffu + ((u >> 16) & 1u)) >> 16);
}
DEV unsigned pack2(float lo, float hi) {
    return ((unsigned)f2bf(hi) << 16) | (unsigned)f2bf(lo);
}
DEV f32x4 mfma16(short8v a, short8v b, f32x4 c) {
    return __builtin_amdgcn_mfma_f32_16x16x32_bf16(a, b, c, 0, 0, 0);
}

// Exact-GELU via Abramowitz-Stegun 7.1.26 erf (|err| <= 1.5e-7), ~16 VALU ops.
DEV float gelu_fast(float x) {
    const float z  = x * 0.70710678118654752f;
    const float az = fabsf(z);
    const float t  = __builtin_amdgcn_rcpf(fmaf(0.3275911f, az, 1.0f));
    float p = fmaf(t, 1.061405429f, -1.453152027f);
    p = fmaf(t, p, 1.421413741f);
    p = fmaf(t, p, -0.284496736f);
    p = fmaf(t, p, 0.254829592f);
    p = p * t;
    const float E = __builtin_amdgcn_exp2f(z * z * -1.4426950408889634f);
    const float erf_az = fmaf(-p, E, 1.0f);
    const float erf_z  = copysignf(erf_az, z);
    const float hx = 0.5f * x;
    return fmaf(hx, erf_z, hx);
}

#define NN 2048

// ==================================================================
// prep (65 blocks): W1 -> W1T bf16 [256][128]; W2 cols0..127 -> W2T
// bf16 [128][256]; w2col = W2[:,128].  (sort moved into p1's grid)
// ==================================================================
__global__ __launch_bounds__(256, 1) void prep_kernel(
    const float* __restrict__ W1, const float* __restrict__ W2,
    unsigned short* __restrict__ W1T, unsigned short* __restrict__ W2T,
    float* __restrict__ w2col)
{
    __shared__ __align__(16) float T[32][33];
    const int tid = threadIdx.x;
    const int bid = blockIdx.x;

    if (bid < 32) {
        const int tr = bid >> 3, tc = bid & 7;
#pragma unroll
        for (int p = 0; p < 4; p++) {
            const int i = p * 8 + (tid >> 5), j = tid & 31;
            T[i][j] = W1[(tr * 32 + i) * 256 + tc * 32 + j];
        }
        __syncthreads();
#pragma unroll
        for (int p = 0; p < 4; p++) {
            const int i = p * 8 + (tid >> 5), j = tid & 31;
            W1T[(tc * 32 + i) * 128 + tr * 32 + j] = f2bf(T[j][i]);
        }
    } else if (bid < 64) {
        const int bb = bid - 32, tr = bb >> 2, tc = bb & 3;
#pragma unroll
        for (int p = 0; p < 4; p++) {
            const int i = p * 8 + (tid >> 5), j = tid & 31;
            T[i][j] = W2[(tr * 32 + i) * 129 + tc * 32 + j];
        }
        __syncthreads();
#pragma unroll
        for (int p = 0; p < 4; p++) {
            const int i = p * 8 + (tid >> 5), j = tid & 31;
            W2T[(tc * 32 + i) * 256 + tr * 32 + j] = f2bf(T[j][i]);
        }
    } else {
        w2col[tid] = W2[tid * 129 + 128];
    }
}

// ==================================================================
// p1: blocks 0..511 = per-(b,n) hypernetwork via bf16 MFMA (16 rows
// each, exact R14 form). Blocks 512..515 = per-b counting sort of
// neurons by slot (outputs only needed by p2) — runs concurrently.
// ==================================================================
__global__ __launch_bounds__(256, 1) void p1_kernel(
    const int* __restrict__ neuron_regions, const int* __restrict__ eids,
    const int* __restrict__ r_map,
    const float* __restrict__ neuron_slot, const float* __restrict__ region_emb,
    const float* __restrict__ eid_emb, const float* __restrict__ ln_gamma,
    const float* __restrict__ ln_beta, const float* __restrict__ b1,
    const float* __restrict__ b2, const unsigned short* __restrict__ W1T,
    const unsigned short* __restrict__ W2T, const float* __restrict__ w2col,
    unsigned short* __restrict__ w_ws, float* __restrict__ bias_ws,
    int* __restrict__ order, int* __restrict__ offs)
{
    __shared__ __align__(16) unsigned short hT[16][136];   // h bf16 (also out-bounce)
    __shared__ __align__(16) unsigned short H1[16][264];   // gelu(hW1+b1) bf16
    __shared__ float biasp[16];
    __shared__ int hist[65], starts[66], cursor[65];
    const int tid = threadIdx.x;
    const int bid = blockIdx.x;

    if (bid >= 512) {   // ---- counting-sort duty (concurrent with hypernet) ----
        const int b = bid - 512;
        for (int i = tid; i < 65; i += 256) hist[i] = 0;
        __syncthreads();
        for (int n = tid; n < NN; n += 256) {
            int nr = min(max(neuron_regions[b * NN + n], 0), 127);
            int lr = r_map[nr];
            int bin = (lr < 0) ? 64 : min(lr, 63);
            atomicAdd(&hist[bin], 1);
        }
        __syncthreads();
        if (tid == 0) {
            int run = 0;
            for (int i = 0; i < 65; i++) { starts[i] = run; cursor[i] = run; run += hist[i]; }
            starts[65] = run;
        }
        __syncthreads();
        for (int i = tid; i < 66; i += 256) offs[b * 66 + i] = starts[i];
        for (int n = tid; n < NN; n += 256) {
            int nr = min(max(neuron_regions[b * NN + n], 0), 127);
            int lr = r_map[nr];
            int bin = (lr < 0) ? 64 : min(lr, 63);
            int pos = atomicAdd(&cursor[bin], 1);
            order[b * NN + pos] = n;
        }
        return;
    }

    const int row0 = bid * 16;
    if (tid < 16) biasp[tid] = 0.f;

    // ---------- Stage A: e + LayerNorm -> hT ----------
    {
        const int rr = tid >> 4, q = tid & 15;    // 16 rows x 16 lanes
        const int row = row0 + rr;
        const int b = row >> 11, n = row & (NN - 1);
        int nr = min(max(neuron_regions[b * NN + n], 0), 127);
        int eid = min(max(eids[b], 0), 255);
        const float* ns = neuron_slot + n * 128 + q * 8;
        const float* re = region_emb + nr * 128 + q * 8;
        const float* ee = eid_emb + eid * 128 + q * 8;
        float e[8];
        {
            float4 a0 = *(const float4*)ns, a1 = *(const float4*)(ns + 4);
            float4 c0 = *(const float4*)re, c1 = *(const float4*)(re + 4);
            float4 d0 = *(const float4*)ee, d1 = *(const float4*)(ee + 4);
            e[0] = a0.x + c0.x + d0.x; e[1] = a0.y + c0.y + d0.y;
            e[2] = a0.z + c0.z + d0.z; e[3] = a0.w + c0.w + d0.w;
            e[4] = a1.x + c1.x + d1.x; e[5] = a1.y + c1.y + d1.y;
            e[6] = a1.z + c1.z + d1.z; e[7] = a1.w + c1.w + d1.w;
        }
        float s = 0.f, s2 = 0.f;
#pragma unroll
        for (int i = 0; i < 8; i++) { s += e[i]; s2 += e[i] * e[i]; }
        s += __shfl_xor(s, 1);  s2 += __shfl_xor(s2, 1);
        s += __shfl_xor(s, 2);  s2 += __shfl_xor(s2, 2);
        s += __shfl_xor(s, 4);  s2 += __shfl_xor(s2, 4);
        s += __shfl_xor(s, 8);  s2 += __shfl_xor(s2, 8);
        const float mu = s * (1.f / 128.f);
        const float var = s2 * (1.f / 128.f) - mu * mu;
        const float rstd = rsqrtf(var + 1e-5f);
        float4 g0 = *(const float4*)(ln_gamma + q * 8), g1 = *(const float4*)(ln_gamma + q * 8 + 4);
        float4 t0 = *(const float4*)(ln_beta + q * 8),  t1 = *(const float4*)(ln_beta + q * 8 + 4);
        float gm[8] = {g0.x, g0.y, g0.z, g0.w, g1.x, g1.y, g1.z, g1.w};
        float bt[8] = {t0.x, t0.y, t0.z, t0.w, t1.x, t1.y, t1.z, t1.w};
        float h[8];
#pragma unroll
        for (int i = 0; i < 8; i++) h[i] = (e[i] - mu) * rstd * gm[i] + bt[i];
        uint4 pk;
        pk.x = pack2(h[0], h[1]); pk.y = pack2(h[2], h[3]);
        pk.z = pack2(h[4], h[5]); pk.w = pack2(h[6], h[7]);
        *(uint4*)&hT[rr][q * 8] = pk;
    }
    __syncthreads();

    const int wv = tid >> 6, l = tid & 63;
    const int lr = l & 15, lh = l >> 4;

    // ---------- GEMM1: C1[16x256] = h @ W1  (wave wv owns cols wv*64..+63) ----------
    short8v afr[4];
#pragma unroll
    for (int ks = 0; ks < 4; ks++)
        afr[ks] = *(const short8v*)&hT[lr][ks * 32 + lh * 8];

    f32x4 acc1[4];
    short8v bfr[4][4];
    float w2c[4];
#pragma unroll
    for (int nt = 0; nt < 4; nt++) {
        const int n = wv * 64 + nt * 16 + lr;
#pragma unroll
        for (int ks = 0; ks < 4; ks++)
            bfr[nt][ks] = *(const short8v*)(W1T + n * 128 + ks * 32 + lh * 8);
        const float bb = b1[n];
        acc1[nt].x = bb; acc1[nt].y = bb; acc1[nt].z = bb; acc1[nt].w = bb;
        w2c[nt] = w2col[n];
    }
#pragma unroll
    for (int nt = 0; nt < 4; nt++)
#pragma unroll
        for (int ks = 0; ks < 4; ks++)
            acc1[nt] = mfma16(afr[ks], bfr[nt][ks], acc1[nt]);

    // ---------- GELU -> H1 (bf16) + bias-column partials ----------
    float pb[4] = {0.f, 0.f, 0.f, 0.f};
#pragma unroll
    for (int nt = 0; nt < 4; nt++) {
        const int n = wv * 64 + nt * 16 + lr;
#pragma unroll
        for (int j = 0; j < 4; j++) {
            const float g = gelu_fast(acc1[nt][j]);
            H1[lh * 4 + j][n] = f2bf(g);
            pb[j] += g * w2c[nt];
        }
    }
#pragma unroll
    for (int j = 0; j < 4; j++) {
        pb[j] += __shfl_xor(pb[j], 1);
        pb[j] += __shfl_xor(pb[j], 2);
        pb[j] += __shfl_xor(pb[j], 4);
        pb[j] += __shfl_xor(pb[j], 8);
    }
    if (lr == 0) {
#pragma unroll
        for (int j = 0; j < 4; j++) atomicAdd(&biasp[lh * 4 + j], pb[j]);
    }
    __syncthreads();

    if (tid < 16) bias_ws[row0 + tid] = biasp[tid] + b2[128];

    // ---------- GEMM2: C2[16x128] = H1 @ W2  (wave wv owns cols wv*32..+31) ----------
    short8v a2[8];
#pragma unroll
    for (int ks = 0; ks < 8; ks++)
        a2[ks] = *(const short8v*)&H1[lr][ks * 32 + lh * 8];

    f32x4 acc2[2];
    short8v b2f[2][8];
#pragma unroll
    for (int nt = 0; nt < 2; nt++) {
        const int n = wv * 32 + nt * 16 + lr;
#pragma unroll
        for (int ks = 0; ks < 8; ks++)
            b2f[nt][ks] = *(const short8v*)(W2T + n * 256 + ks * 32 + lh * 8);
        const float bb = b2[n];
        acc2[nt].x = bb; acc2[nt].y = bb; acc2[nt].z = bb; acc2[nt].w = bb;
    }
#pragma unroll
    for (int nt = 0; nt < 2; nt++)
#pragma unroll
        for (int ks = 0; ks < 8; ks++)
            acc2[nt] = mfma16(a2[ks], b2f[nt][ks], acc2[nt]);

    // ---------- bounce C2 through LDS (reuse hT), coalesced store ----------
#pragma unroll
    for (int nt = 0; nt < 2; nt++) {
        const int n = wv * 32 + nt * 16 + lr;
#pragma unroll
        for (int j = 0; j < 4; j++)
            hT[lh * 4 + j][n] = f2bf(acc2[nt][j]);
    }
    __syncthreads();
    {
        const int r = tid >> 4, c = tid & 15;
        uint4 v = *(const uint4*)&hT[r][c * 8];
        *(uint4*)(w_ws + (row0 + r) * 128 + c * 8) = v;
    }
}

// ==================================================================
// p2: blocks 0..1023 = (b, slot, t-quarter) gather-GEMM with chunk
// loop; blocks 1024..1027 dead-zero. ~4 blocks/CU (17.7 KB LDS).
// Wave wv: row-tile (wv>>1), neuron-half (wv&1).  (exact R18 form)
// ==================================================================
__global__ __launch_bounds__(256, 1) void p2_kernel(
    const float* __restrict__ U, const int* __restrict__ order,
    const int* __restrict__ offs, const unsigned short* __restrict__ w_ws,
    const float* __restrict__ bias_ws, float* __restrict__ out)
{
    __shared__ __align__(16) unsigned short Ubf[32][136];
    __shared__ __align__(16) unsigned short Bt[32][136];
    __shared__ int nidS[32];
    __shared__ float biasS[32];
    const int tid = threadIdx.x;
    const int bid = blockIdx.x;

    if (bid >= 1024) {   // dead neurons -> zeros (no-op when none)
        const int b = bid - 1024;
        const int s64 = offs[b * 66 + 64], s65 = offs[b * 66 + 65];
        const int cnt = s65 - s64;
        for (int idx = tid; idx < cnt * 128; idx += 256) {
            const int j = idx >> 7, t = idx & 127;
            const int n = order[b * NN + s64 + j];
            out[(size_t)(b * 128 + t) * NN + n] = 0.f;
        }
        return;
    }

    const int b = bid >> 8, rem = bid & 255;
    const int slot = rem >> 2, tq = rem & 3;
    const int t0 = tq * 32;
    const int s0 = offs[b * 66 + slot], s1 = offs[b * 66 + slot + 1];
    const int cnt = s1 - s0;
    if (cnt <= 0) return;

    // stage U[b, t0..t0+31, slot, :] as bf16 (32 rows x 8 lanes x 16 floats)
    {
        const int t = tid >> 3, q = tid & 7;
        const float* src = U + ((size_t)((b * 128 + t0 + t) * 64 + slot)) * 128 + q * 16;
        unsigned short* dst = &Ubf[t][q * 16];
        float4 v0 = ((const float4*)src)[0], v1 = ((const float4*)src)[1];
        float4 v2 = ((const float4*)src)[2], v3 = ((const float4*)src)[3];
        uint4 pkA, pkB;
        pkA.x = pack2(v0.x, v0.y); pkA.y = pack2(v0.z, v0.w);
        pkA.z = pack2(v1.x, v1.y); pkA.w = pack2(v1.z, v1.w);
        pkB.x = pack2(v2.x, v2.y); pkB.y = pack2(v2.z, v2.w);
        pkB.z = pack2(v3.x, v3.y); pkB.w = pack2(v3.z, v3.w);
        ((uint4*)dst)[0] = pkA;
        ((uint4*)dst)[1] = pkB;
    }
    __syncthreads();

    const int wv = tid >> 6, l = tid & 63;
    const int lr = l & 15, lh = l >> 4;
    const int rtile = wv >> 1, nhalf = wv & 1;

    // decode A-fragments: wave's row-tile (16 t-rows)
    short8v afr[4];
#pragma unroll
    for (int ks = 0; ks < 4; ks++)
        afr[ks] = *(const short8v*)&Ubf[rtile * 16 + lr][ks * 32 + lh * 8];

    const int nChunks = (cnt + 31) >> 5;
    for (int c = 0; c < nChunks; c++) {
        const int base = s0 + c * 32;
        const int cc = min(cnt - c * 32, 32);
        __syncthreads();   // previous chunk's Bt/nidS reads complete
        if (tid < 32) {
            const int nid = (tid < cc) ? order[b * NN + base + tid] : -1;
            nidS[tid] = nid;
            biasS[tid] = (nid >= 0) ? bias_ws[b * NN + nid] : 0.f;
        }
        {
            const int jj = tid >> 3, q = tid & 7;
            const int nid = (jj < cc) ? order[b * NN + base + jj] : -1;
            unsigned short* dst = &Bt[jj][q * 16];
            if (nid >= 0) {
                const uint4* src = (const uint4*)(w_ws + ((size_t)(b * NN + nid)) * 128 + q * 16);
                ((uint4*)dst)[0] = src[0];
                ((uint4*)dst)[1] = src[1];
            } else {
                ((uint4*)dst)[0] = make_uint4(0, 0, 0, 0);
                ((uint4*)dst)[1] = make_uint4(0, 0, 0, 0);
            }
        }
        __syncthreads();

        // B-fragments: wave's neuron-half (16 neurons)
        short8v bfr[4];
#pragma unroll
        for (int ks = 0; ks < 4; ks++)
            bfr[ks] = *(const short8v*)&Bt[nhalf * 16 + lr][ks * 32 + lh * 8];

        f32x4 a; a.x = 0.f; a.y = 0.f; a.z = 0.f; a.w = 0.f;
#pragma unroll
        for (int ks = 0; ks < 4; ks++) a = mfma16(afr[ks], bfr[ks], a);

        const int j = nhalf * 16 + lr;
        const int nid = nidS[j];
        if (nid >= 0) {
            const float bs = biasS[j];
#pragma unroll
            for (int jr = 0; jr < 4; jr++)
                out[(size_t)(b * 128 + t0 + rtile * 16 + lh * 4 + jr) * NN + nid] =
                    a[jr] + bs;
        }
    }
}

extern "C" void kernel_launch(void* const* d_in, const int* in_sizes, int n_in,
                              void* d_out, int out_size, void* d_ws, size_t ws_size,
                              hipStream_t stream)
{
    const float* U              = (const float*)d_in[0];
    const int*   neuron_regions = (const int*)d_in[1];
    const int*   eids           = (const int*)d_in[2];
    const int*   r_map          = (const int*)d_in[3];
    const float* neuron_slot    = (const float*)d_in[4];
    const float* region_emb     = (const float*)d_in[5];
    const float* eid_emb        = (const float*)d_in[6];
    const float* ln_gamma       = (const float*)d_in[7];
    const float* ln_beta        = (const float*)d_in[8];
    const float* W1             = (const float*)d_in[9];
    const float* b1             = (const float*)d_in[10];
    const float* W2             = (const float*)d_in[11];
    const float* b2             = (const float*)d_in[12];

    char* ws = (char*)d_ws;
    unsigned short* w_ws    = (unsigned short*)(ws);               // 2 MiB
    float*          bias_ws = (float*)(ws + 0x200000);             // 32 KiB
    unsigned short* W1T     = (unsigned short*)(ws + 0x208000);    // 64 KiB
    unsigned short* W2T     = (unsigned short*)(ws + 0x218000);    // 64 KiB
    float*          w2col   = (float*)(ws + 0x228000);             // 1 KiB
    int*            order   = (int*)(ws + 0x229000);               // 32 KiB
    int*            offs    = (int*)(ws + 0x231000);               // ~1 KiB
    float* outp = (float*)d_out;

    hipLaunchKernelGGL(prep_kernel, dim3(65), dim3(256), 0, stream,
                       W1, W2, W1T, W2T, w2col);
    hipLaunchKernelGGL(p1_kernel, dim3(516), dim3(256), 0, stream,
                       neuron_regions, eids, r_map, neuron_slot, region_emb,
                       eid_emb, ln_gamma, ln_beta, b1, b2, W1T, W2T, w2col,
                       w_ws, bias_ws, order, offs);
    hipLaunchKernelGGL(p2_kernel, dim3(1028), dim3(256), 0, stream,
                       U, order, offs, w_ws, bias_ws, outp);
}

// Round 20
// 35.874 us; speedup vs baseline: 1.0133x; 1.0133x over previous
//
#include <hip/hip_runtime.h>
#include <hip/hip_bf16.h>
#include <math.h>

#define DEV __device__ __forceinline__

typedef __attribute__((ext_vector_type(8))) short short8v;
typedef __attribute__((ext_vector_type(4))) float f32x4;

DEV unsigned short f2bf(float x) {
    unsigned u = __float_as_uint(x);
    return (unsigned short)((u + 0x7fffu + ((u >> 16) & 1u)) >> 16);
}
DEV unsigned pack2(float lo, float hi) {
    return ((unsigned)f2bf(hi) << 16) | (unsigned)f2bf(lo);
}
DEV f32x4 mfma16(short8v a, short8v b, f32x4 c) {
    return __builtin_amdgcn_mfma_f32_16x16x32_bf16(a, b, c, 0, 0, 0);
}

// Exact-GELU via Abramowitz-Stegun 7.1.26 erf (|err| <= 1.5e-7), ~16 VALU ops.
DEV float gelu_fast(float x) {
    const float z  = x * 0.70710678118654752f;
    const float az = fabsf(z);
    const float t  = __builtin_amdgcn_rcpf(fmaf(0.3275911f, az, 1.0f));
    float p = fmaf(t, 1.061405429f, -1.453152027f);
    p = fmaf(t, p, 1.421413741f);
    p = fmaf(t, p, -0.284496736f);
    p = fmaf(t, p, 0.254829592f);
    p = p * t;
    const float E = __builtin_amdgcn_exp2f(z * z * -1.4426950408889634f);
    const float erf_az = fmaf(-p, E, 1.0f);
    const float erf_z  = copysignf(erf_az, z);
    const float hx = 0.5f * x;
    return fmaf(hx, erf_z, hx);
}

#define NN 2048

// ==================================================================
// prep: blocks 0..31  W1[128][256] -> W1T bf16 [256][128]
//       blocks 32..63 W2[256][129] cols0..127 -> W2T bf16 [128][256]
//       block  64     w2col[256] = W2[:,128] (f32)
//       blocks 65..68 counting sort of neurons by local region (per b)
// ==================================================================
__global__ __launch_bounds__(256, 1) void prep_kernel(
    const float* __restrict__ W1, const float* __restrict__ W2,
    const int* __restrict__ r_map, const int* __restrict__ neuron_regions,
    unsigned short* __restrict__ W1T, unsigned short* __restrict__ W2T,
    float* __restrict__ w2col, int* __restrict__ order, int* __restrict__ offs)
{
    __shared__ __align__(16) float T[32][33];
    __shared__ int hist[65], starts[66], cursor[65];
    const int tid = threadIdx.x;
    const int bid = blockIdx.x;

    if (bid < 32) {
        const int tr = bid >> 3, tc = bid & 7;
#pragma unroll
        for (int p = 0; p < 4; p++) {
            const int i = p * 8 + (tid >> 5), j = tid & 31;
            T[i][j] = W1[(tr * 32 + i) * 256 + tc * 32 + j];
        }
        __syncthreads();
#pragma unroll
        for (int p = 0; p < 4; p++) {
            const int i = p * 8 + (tid >> 5), j = tid & 31;
            W1T[(tc * 32 + i) * 128 + tr * 32 + j] = f2bf(T[j][i]);
        }
    } else if (bid < 64) {
        const int bb = bid - 32, tr = bb >> 2, tc = bb & 3;
#pragma unroll
        for (int p = 0; p < 4; p++) {
            const int i = p * 8 + (tid >> 5), j = tid & 31;
            T[i][j] = W2[(tr * 32 + i) * 129 + tc * 32 + j];
        }
        __syncthreads();
#pragma unroll
        for (int p = 0; p < 4; p++) {
            const int i = p * 8 + (tid >> 5), j = tid & 31;
            W2T[(tc * 32 + i) * 256 + tr * 32 + j] = f2bf(T[j][i]);
        }
    } else if (bid == 64) {
        w2col[tid] = W2[tid * 129 + 128];
    } else {
        const int b = bid - 65;
        for (int i = tid; i < 65; i += 256) hist[i] = 0;
        __syncthreads();
        for (int n = tid; n < NN; n += 256) {
            int nr = min(max(neuron_regions[b * NN + n], 0), 127);
            int lr = r_map[nr];
            int bin = (lr < 0) ? 64 : min(lr, 63);
            atomicAdd(&hist[bin], 1);
        }
        __syncthreads();
        if (tid == 0) {
            int run = 0;
            for (int i = 0; i < 65; i++) { starts[i] = run; cursor[i] = run; run += hist[i]; }
            starts[65] = run;
        }
        __syncthreads();
        for (int i = tid; i < 66; i += 256) offs[b * 66 + i] = starts[i];
        for (int n = tid; n < NN; n += 256) {
            int nr = min(max(neuron_regions[b * NN + n], 0), 127);
            int lr = r_map[nr];
            int bin = (lr < 0) ? 64 : min(lr, 63);
            int pos = atomicAdd(&cursor[bin], 1);
            order[b * NN + pos] = n;
        }
    }
}

// ==================================================================
// p1: per-(b,n) hypernetwork via bf16 MFMA. 512 blocks x 16 rows.
// B-fragments streamed + __launch_bounds__(256,2): 2 blocks/CU.
// ==================================================================
__global__ __launch_bounds__(256, 2) void p1_kernel(
    const int* __restrict__ neuron_regions, const int* __restrict__ eids,
    const float* __restrict__ neuron_slot, const float* __restrict__ region_emb,
    const float* __restrict__ eid_emb, const float* __restrict__ ln_gamma,
    const float* __restrict__ ln_beta, const float* __restrict__ b1,
    const float* __restrict__ b2, const unsigned short* __restrict__ W1T,
    const unsigned short* __restrict__ W2T, const float* __restrict__ w2col,
    unsigned short* __restrict__ w_ws, float* __restrict__ bias_ws)
{
    __shared__ __align__(16) unsigned short hT[16][136];   // h bf16 (also out-bounce)
    __shared__ __align__(16) unsigned short H1[16][264];   // gelu(hW1+b1) bf16
    __shared__ float biasp[16];
    const int tid = threadIdx.x;
    const int row0 = blockIdx.x * 16;
    if (tid < 16) biasp[tid] = 0.f;

    // ---------- Stage A: e + LayerNorm -> hT ----------
    {
        const int rr = tid >> 4, q = tid & 15;    // 16 rows x 16 lanes
        const int row = row0 + rr;
        const int b = row >> 11, n = row & (NN - 1);
        int nr = min(max(neuron_regions[b * NN + n], 0), 127);
        int eid = min(max(eids[b], 0), 255);
        const float* ns = neuron_slot + n * 128 + q * 8;
        const float* re = region_emb + nr * 128 + q * 8;
        const float* ee = eid_emb + eid * 128 + q * 8;
        float e[8];
        {
            float4 a0 = *(const float4*)ns, a1 = *(const float4*)(ns + 4);
            float4 c0 = *(const float4*)re, c1 = *(const float4*)(re + 4);
            float4 d0 = *(const float4*)ee, d1 = *(const float4*)(ee + 4);
            e[0] = a0.x + c0.x + d0.x; e[1] = a0.y + c0.y + d0.y;
            e[2] = a0.z + c0.z + d0.z; e[3] = a0.w + c0.w + d0.w;
            e[4] = a1.x + c1.x + d1.x; e[5] = a1.y + c1.y + d1.y;
            e[6] = a1.z + c1.z + d1.z; e[7] = a1.w + c1.w + d1.w;
        }
        float s = 0.f, s2 = 0.f;
#pragma unroll
        for (int i = 0; i < 8; i++) { s += e[i]; s2 += e[i] * e[i]; }
        s += __shfl_xor(s, 1);  s2 += __shfl_xor(s2, 1);
        s += __shfl_xor(s, 2);  s2 += __shfl_xor(s2, 2);
        s += __shfl_xor(s, 4);  s2 += __shfl_xor(s2, 4);
        s += __shfl_xor(s, 8);  s2 += __shfl_xor(s2, 8);
        const float mu = s * (1.f / 128.f);
        const float var = s2 * (1.f / 128.f) - mu * mu;
        const float rstd = rsqrtf(var + 1e-5f);
        float4 g0 = *(const float4*)(ln_gamma + q * 8), g1 = *(const float4*)(ln_gamma + q * 8 + 4);
        float4 t0 = *(const float4*)(ln_beta + q * 8),  t1 = *(const float4*)(ln_beta + q * 8 + 4);
        float gm[8] = {g0.x, g0.y, g0.z, g0.w, g1.x, g1.y, g1.z, g1.w};
        float bt[8] = {t0.x, t0.y, t0.z, t0.w, t1.x, t1.y, t1.z, t1.w};
        float h[8];
#pragma unroll
        for (int i = 0; i < 8; i++) h[i] = (e[i] - mu) * rstd * gm[i] + bt[i];
        uint4 pk;
        pk.x = pack2(h[0], h[1]); pk.y = pack2(h[2], h[3]);
        pk.z = pack2(h[4], h[5]); pk.w = pack2(h[6], h[7]);
        *(uint4*)&hT[rr][q * 8] = pk;
    }
    __syncthreads();

    const int wv = tid >> 6, l = tid & 63;
    const int lr = l & 15, lh = l >> 4;

    // ---------- GEMM1: C1[16x256] = h @ W1 (B-fragments streamed) ----------
    short8v afr[4];
#pragma unroll
    for (int ks = 0; ks < 4; ks++)
        afr[ks] = *(const short8v*)&hT[lr][ks * 32 + lh * 8];

    // ---------- GELU -> H1 (bf16) + bias-column partials ----------
    float pb[4] = {0.f, 0.f, 0.f, 0.f};
#pragma unroll
    for (int nt = 0; nt < 4; nt++) {
        const int n = wv * 64 + nt * 16 + lr;
        short8v bfr[4];
#pragma unroll
        for (int ks = 0; ks < 4; ks++)
            bfr[ks] = *(const short8v*)(W1T + n * 128 + ks * 32 + lh * 8);
        const float bb = b1[n];
        const float w2cv = w2col[n];
        f32x4 a; a.x = bb; a.y = bb; a.z = bb; a.w = bb;
#pragma unroll
        for (int ks = 0; ks < 4; ks++) a = mfma16(afr[ks], bfr[ks], a);
#pragma unroll
        for (int j = 0; j < 4; j++) {
            const float g = gelu_fast(a[j]);
            H1[lh * 4 + j][n] = f2bf(g);
            pb[j] += g * w2cv;
        }
    }
#pragma unroll
    for (int j = 0; j < 4; j++) {
        pb[j] += __shfl_xor(pb[j], 1);
        pb[j] += __shfl_xor(pb[j], 2);
        pb[j] += __shfl_xor(pb[j], 4);
        pb[j] += __shfl_xor(pb[j], 8);
    }
    if (lr == 0) {
#pragma unroll
        for (int j = 0; j < 4; j++) atomicAdd(&biasp[lh * 4 + j], pb[j]);
    }
    __syncthreads();

    if (tid < 16) bias_ws[row0 + tid] = biasp[tid] + b2[128];

    // ---------- GEMM2: C2[16x128] = H1 @ W2 (B-fragments streamed) ----------
    short8v a2[8];
#pragma unroll
    for (int ks = 0; ks < 8; ks++)
        a2[ks] = *(const short8v*)&H1[lr][ks * 32 + lh * 8];

    f32x4 acc2[2];
#pragma unroll
    for (int nt = 0; nt < 2; nt++) {
        const int n = wv * 32 + nt * 16 + lr;
        short8v bf[8];
#pragma unroll
        for (int ks = 0; ks < 8; ks++)
            bf[ks] = *(const short8v*)(W2T + n * 256 + ks * 32 + lh * 8);
        const float bb = b2[n];
        f32x4 a; a.x = bb; a.y = bb; a.z = bb; a.w = bb;
#pragma unroll
        for (int ks = 0; ks < 8; ks++) a = mfma16(a2[ks], bf[ks], a);
        acc2[nt] = a;
    }

    // ---------- bounce C2 through LDS (reuse hT), coalesced store ----------
    __syncthreads();   // all hT (afr source) reads long done; H1 reads done
#pragma unroll
    for (int nt = 0; nt < 2; nt++) {
        const int n = wv * 32 + nt * 16 + lr;
#pragma unroll
        for (int j = 0; j < 4; j++)
            hT[lh * 4 + j][n] = f2bf(acc2[nt][j]);
    }
    __syncthreads();
    {
        const int r = tid >> 4, c = tid & 15;
        uint4 v = *(const uint4*)&hT[r][c * 8];
        *(uint4*)(w_ws + (row0 + r) * 128 + c * 8) = v;
    }
}

// ==================================================================
// p2: blocks 0..1023 = (b, slot, t-quarter) gather-GEMM with chunk
// loop; blocks 1024..1027 dead-zero. ~4 blocks/CU (17.7 KB LDS).
// Wave wv: row-tile (wv>>1), neuron-half (wv&1).  (exact R18 form)
// ==================================================================
__global__ __launch_bounds__(256, 1) void p2_kernel(
    const float* __restrict__ U, const int* __restrict__ order,
    const int* __restrict__ offs, const unsigned short* __restrict__ w_ws,
    const float* __restrict__ bias_ws, float* __restrict__ out)
{
    __shared__ __align__(16) unsigned short Ubf[32][136];
    __shared__ __align__(16) unsigned short Bt[32][136];
    __shared__ int nidS[32];
    __shared__ float biasS[32];
    const int tid = threadIdx.x;
    const int bid = blockIdx.x;

    if (bid >= 1024) {   // dead neurons -> zeros (no-op when none)
        const int b = bid - 1024;
        const int s64 = offs[b * 66 + 64], s65 = offs[b * 66 + 65];
        const int cnt = s65 - s64;
        for (int idx = tid; idx < cnt * 128; idx += 256) {
            const int j = idx >> 7, t = idx & 127;
            const int n = order[b * NN + s64 + j];
            out[(size_t)(b * 128 + t) * NN + n] = 0.f;
        }
        return;
    }

    const int b = bid >> 8, rem = bid & 255;
    const int slot = rem >> 2, tq = rem & 3;
    const int t0 = tq * 32;
    const int s0 = offs[b * 66 + slot], s1 = offs[b * 66 + slot + 1];
    const int cnt = s1 - s0;
    if (cnt <= 0) return;

    // stage U[b, t0..t0+31, slot, :] as bf16 (32 rows x 8 lanes x 16 floats)
    {
        const int t = tid >> 3, q = tid & 7;
        const float* src = U + ((size_t)((b * 128 + t0 + t) * 64 + slot)) * 128 + q * 16;
        unsigned short* dst = &Ubf[t][q * 16];
        float4 v0 = ((const float4*)src)[0], v1 = ((const float4*)src)[1];
        float4 v2 = ((const float4*)src)[2], v3 = ((const float4*)src)[3];
        uint4 pkA, pkB;
        pkA.x = pack2(v0.x, v0.y); pkA.y = pack2(v0.z, v0.w);
        pkA.z = pack2(v1.x, v1.y); pkA.w = pack2(v1.z, v1.w);
        pkB.x = pack2(v2.x, v2.y); pkB.y = pack2(v2.z, v2.w);
        pkB.z = pack2(v3.x, v3.y); pkB.w = pack2(v3.z, v3.w);
        ((uint4*)dst)[0] = pkA;
        ((uint4*)dst)[1] = pkB;
    }
    __syncthreads();

    const int wv = tid >> 6, l = tid & 63;
    const int lr = l & 15, lh = l >> 4;
    const int rtile = wv >> 1, nhalf = wv & 1;

    // decode A-fragments: wave's row-tile (16 t-rows)
    short8v afr[4];
#pragma unroll
    for (int ks = 0; ks < 4; ks++)
        afr[ks] = *(const short8v*)&Ubf[rtile * 16 + lr][ks * 32 + lh * 8];

    const int nChunks = (cnt + 31) >> 5;
    for (int c = 0; c < nChunks; c++) {
        const int base = s0 + c * 32;
        const int cc = min(cnt - c * 32, 32);
        __syncthreads();   // previous chunk's Bt/nidS reads complete
        if (tid < 32) {
            const int nid = (tid < cc) ? order[b * NN + base + tid] : -1;
            nidS[tid] = nid;
            biasS[tid] = (nid >= 0) ? bias_ws[b * NN + nid] : 0.f;
        }
        {
            const int jj = tid >> 3, q = tid & 7;
            const int nid = (jj < cc) ? order[b * NN + base + jj] : -1;
            unsigned short* dst = &Bt[jj][q * 16];
            if (nid >= 0) {
                const uint4* src = (const uint4*)(w_ws + ((size_t)(b * NN + nid)) * 128 + q * 16);
                ((uint4*)dst)[0] = src[0];
                ((uint4*)dst)[1] = src[1];
            } else {
                ((uint4*)dst)[0] = make_uint4(0, 0, 0, 0);
                ((uint4*)dst)[1] = make_uint4(0, 0, 0, 0);
            }
        }
        __syncthreads();

        // B-fragments: wave's neuron-half (16 neurons)
        short8v bfr[4];
#pragma unroll
        for (int ks = 0; ks < 4; ks++)
            bfr[ks] = *(const short8v*)&Bt[nhalf * 16 + lr][ks * 32 + lh * 8];

        f32x4 a; a.x = 0.f; a.y = 0.f; a.z = 0.f; a.w = 0.f;
#pragma unroll
        for (int ks = 0; ks < 4; ks++) a = mfma16(afr[ks], bfr[ks], a);

        const int j = nhalf * 16 + lr;
        const int nid = nidS[j];
        if (nid >= 0) {
            const float bs = biasS[j];
#pragma unroll
            for (int jr = 0; jr < 4; jr++)
                out[(size_t)(b * 128 + t0 + rtile * 16 + lh * 4 + jr) * NN + nid] =
                    a[jr] + bs;
        }
    }
}

extern "C" void kernel_launch(void* const* d_in, const int* in_sizes, int n_in,
                              void* d_out, int out_size, void* d_ws, size_t ws_size,
                              hipStream_t stream)
{
    const float* U              = (const float*)d_in[0];
    const int*   neuron_regions = (const int*)d_in[1];
    const int*   eids           = (const int*)d_in[2];
    const int*   r_map          = (const int*)d_in[3];
    const float* neuron_slot    = (const float*)d_in[4];
    const float* region_emb     = (const float*)d_in[5];
    const float* eid_emb        = (const float*)d_in[6];
    const float* ln_gamma       = (const float*)d_in[7];
    const float* ln_beta        = (const float*)d_in[8];
    const float* W1             = (const float*)d_in[9];
    const float* b1             = (const float*)d_in[10];
    const float* W2             = (const float*)d_in[11];
    const float* b2             = (const float*)d_in[12];

    char* ws = (char*)d_ws;
    unsigned short* w_ws    = (unsigned short*)(ws);               // 2 MiB
    float*          bias_ws = (float*)(ws + 0x200000);             // 32 KiB
    unsigned short* W1T     = (unsigned short*)(ws + 0x208000);    // 64 KiB
    unsigned short* W2T     = (unsigned short*)(ws + 0x218000);    // 64 KiB
    float*          w2col   = (float*)(ws + 0x228000);             // 1 KiB
    int*            order   = (int*)(ws + 0x229000);               // 32 KiB
    int*            offs    = (int*)(ws + 0x231000);               // ~1 KiB
    float* outp = (float*)d_out;

    hipLaunchKernelGGL(prep_kernel, dim3(69), dim3(256), 0, stream,
                       W1, W2, r_map, neuron_regions, W1T, W2T, w2col, order, offs);
    hipLaunchKernelGGL(p1_kernel, dim3(512), dim3(256), 0, stream,
                       neuron_regions, eids, neuron_slot, region_emb, eid_emb,
                       ln_gamma, ln_beta, b1, b2, W1T, W2T, w2col, w_ws, bias_ws);
    hipLaunchKernelGGL(p2_kernel, dim3(1028), dim3(256), 0, stream,
                       U, order, offs, w_ws, bias_ws, outp);
}